// Round 7
// baseline (107.003 us; speedup 1.0000x reference)
//
#include <hip/hip_runtime.h>

#define TOPK 20
#define NITEMS 50000
#define BLOCK 512
#define SPLIT 2
#define HALF_N (NITEMS / SPLIT)        // 25000
#define NH4 (HALF_N / 4)               // 6250
#define NBINS 2048
#define CHUNKS 16
#define STEPS (NBINS / CHUNKS)         // 128
#define XMAX 6.0f
#define SCALE (2048.0f / 12.0f)        // bins per score unit; XMAX*SCALE = 1024
#define DELTA (12.0f / 2048.0f)
#define RSCALE (12.0f / 2048.0f / 4096.0f)   // fixed-point residual -> score units
#define KSTRIDE 0.9105103651f          // exp(-CHUNKS*DELTA) = exp(-0.09375)
#define PSTRIDE 32                     // floats per partial slot (128 B: no cross-XCD line sharing)

// SmoothRank NDCG: per-half-row packed histogram (validated rounds 4-6,
// absmax 4.9e-4 vs 3.65e-3 threshold) + first-order residual correction.
// Round-7 structure: 2 blocks/CU (half-row each) so phase barriers/epilogue
// of one block overlap Phase A of the other; last-arriving block of each row
// finishes the NDCG with a fully parallel wave epilogue (no serial tid==0
// loop, no second dispatch).
__global__ __launch_bounds__(BLOCK) void smoothdcg_kernel(
    const float* __restrict__ scores_top,  // [B][TOPK]
    const float* __restrict__ scores,      // [B][NITEMS]
    const float* __restrict__ labels,      // [B][TOPK]
    float* __restrict__ out,               // [B][TOPK]
    float* __restrict__ partials,          // [B*SPLIT][PSTRIDE]
    unsigned int* __restrict__ counters)   // [B], zeroed by memset on stream
{
    const int bid  = blockIdx.x;
    const int row  = bid >> 1;
    const int half = bid & 1;
    const int tid  = threadIdx.x;

    __shared__ unsigned int hist[NBINS];   // 8 KB packed count|residual
    __shared__ float s_t[TOPK];
    __shared__ int   s_finish;

#pragma unroll
    for (int i = tid; i < NBINS; i += BLOCK) hist[i] = 0u;
    if (tid < TOPK) s_t[tid] = scores_top[row * TOPK + tid];
    __syncthreads();

    // ---- Phase A: packed histogram, one native ds_add_u32 per item ----
    const float4* rp = (const float4*)(scores + (size_t)row * NITEMS + (size_t)half * HALF_N);

    float4 v0 = make_float4(0.f, 0.f, 0.f, 0.f);
    float4 v1 = v0;
    if (tid < NH4)         v0 = rp[tid];
    if (tid + BLOCK < NH4) v1 = rp[tid + BLOCK];

    for (int i = tid; i < NH4; i += BLOCK) {
        float4 v2 = v1;
        const int i2 = i + 2 * BLOCK;
        if (i2 < NH4) v2 = rp[i2];      // 2-deep prefetch: ~2 KB in flight/wave

        float s4[4] = {v0.x, v0.y, v0.z, v0.w};
#pragma unroll
        for (int k = 0; k < 4; ++k) {
            float s = fminf(fmaxf(s4[k], -5.9999f), 5.9999f);
            float f = fmaf(s, SCALE, 1024.0f);        // in (0, 2048)
            int idx  = (int)f;                        // trunc == floor (f > 0)
            float ff = f - (float)idx;                // frac in [0,1)
            unsigned int contrib = (unsigned int)fmaf(ff, 4096.0f, 1048576.0f);
            atomicAdd(&hist[idx], contrib);           // native ds_add_u32
        }
        v0 = v1; v1 = v2;
    }
    __syncthreads();

    // ---- Phase B: partial rank_j over this half's histogram ----
    // thread (j, qc): j = tid>>4 (16-lane group), qc = tid&15; scans bins
    // qc, qc+16, ... (128 bins) with geometric recurrence u *= exp(-16*DELTA).
    if (tid < TOPK * CHUNKS) {  // 320 active
        const int j  = tid >> 4;
        const int qc = tid & 15;
        const float t  = s_t[j];
        const float x0 = fmaf((float)qc + 0.5f, DELTA, -XMAX);
        float u = __expf(t - x0);
        float accW = 0.0f, accQ = 0.0f;
        int m = qc;
#pragma unroll 8
        for (int p = 0; p < STEPS; ++p) {
            unsigned int word = hist[m];
            unsigned int w  = word >> 20;
            int Q = (int)(word & 0xFFFFFu) - (int)(w << 11);
            float sg  = __builtin_amdgcn_rcpf(1.0f + u);  // sigmoid(x_m - t)
            float sgp = fmaf(-sg, sg, sg);                // sig*(1-sig)
            accW = fmaf((float)w, sg, accW);
            accQ = fmaf((float)Q, sgp, accQ);
            u *= KSTRIDE;
            m += CHUNKS;
        }
        float acc = fmaf(accQ, RSCALE, accW);
#pragma unroll
        for (int off = 8; off >= 1; off >>= 1)
            acc += __shfl_down(acc, off, 64);   // 16-lane group reduce
        if (qc == 0) partials[bid * PSTRIDE + j] = acc;
    }

    // ---- completion protocol: last block of the row finishes ----
    __syncthreads();   // barrier drains vmcnt -> partial stores complete
    if (tid == 0) {
        __threadfence();                              // release (L2 writeback)
        unsigned int old = atomicAdd(&counters[row], 1u);
        s_finish = (old == 1);
        if (old == 1) __threadfence();                // acquire (invalidate)
    }
    __syncthreads();

    if (s_finish && tid < 64) {
        const int lane = tid;
        float p = 0.0f, lab = 0.0f;
        if (lane < TOPK) {
            p = partials[(2 * row) * PSTRIDE + lane]
              + partials[(2 * row + 1) * PSTRIDE + lane];
            lab = labels[row * TOPK + lane];
        }
        float rank = p + 0.5f;
        float d  = __log2f(rank + 1.0f);
        float dg = (lane < TOPK) ? lab / d : 0.0f;
        // inclusive prefix sum over lanes 0..19 -> dcg
#pragma unroll
        for (int off = 1; off < 32; off <<= 1) {
            float tmp = __shfl_up(dg, off, 64);
            if (lane >= off) dg += tmp;
        }
        // k_sum via ballot (labels are 0.0/1.0)
        unsigned long long mk = __ballot(lab > 0.5f);
        int ksum = __popcll(mk & 0xFFFFFull);
        // idcg prefix: idcg[lane] = sum_{i<=lane} 1/log2(i+2)
        float r = (lane < TOPK) ? 1.0f / __log2f((float)lane + 2.0f) : 0.0f;
#pragma unroll
        for (int off = 1; off < 32; off <<= 1) {
            float tmp = __shfl_up(r, off, 64);
            if (lane >= off) r += tmp;
        }
        if (lane < TOPK) {
            int kc  = (ksum < lane + 1) ? ksum : (lane + 1);
            int idx = kc - 1;
            if (idx < 0) idx += TOPK;   // JAX negative-index wrap (k_sum==0)
            float iv = __shfl(r, idx, 64);
            out[row * TOPK + lane] = dg / iv;
        }
    }
}

extern "C" void kernel_launch(void* const* d_in, const int* in_sizes, int n_in,
                              void* d_out, int out_size, void* d_ws, size_t ws_size,
                              hipStream_t stream) {
    const float* scores_top = (const float*)d_in[0];
    const float* scores     = (const float*)d_in[1];
    const float* labels     = (const float*)d_in[2];
    float* out              = (float*)d_out;

    const int B = in_sizes[0] / TOPK;  // 256
    float* partials        = (float*)d_ws;                        // 512*32*4 = 64 KB
    unsigned int* counters = (unsigned int*)((char*)d_ws + 65536);

    hipMemsetAsync(counters, 0, B * sizeof(unsigned int), stream);
    smoothdcg_kernel<<<dim3(B * SPLIT), dim3(BLOCK), 0, stream>>>(
        scores_top, scores, labels, out, partials, counters);
}